// Round 16
// baseline (115.778 us; speedup 1.0000x reference)
//
#include <hip/hip_runtime.h>

constexpr int D     = 64;
constexpr int PCAP  = 32;    // primary ELL slots/node = one 64B line
constexpr int CAP   = 64;    // with overflow table; P(deg>64) ~ 0 (Poisson 16)
constexpr int NBUCK = 256;   // buckets (256 nodes each)
constexpr int BNODE = 256;   // nodes per bucket
constexpr int BCAP  = 4480;  // bucket capacity: Poisson(4096) + 6 sigma
constexpr int NBINA = 256;   // binning blocks in mega

typedef __attribute__((ext_vector_type(8))) short          bf16x8;
typedef __attribute__((ext_vector_type(4))) float          f32x4;
typedef __attribute__((ext_vector_type(8))) unsigned short ushort8;
typedef __attribute__((ext_vector_type(4))) unsigned short ushort4v;
typedef __attribute__((ext_vector_type(4))) int            i32x4;

__device__ __forceinline__ unsigned short f2bf(float f) {   // RTN fp32 -> bf16
    unsigned int u = __float_as_uint(f);
    u += 0x7FFFu + ((u >> 16) & 1u);
    return (unsigned short)(u >> 16);
}
__device__ __forceinline__ float bf2f(unsigned short h) {
    return __uint_as_float(((unsigned int)h) << 16);
}
__device__ __forceinline__ void acc4(float& x, float& y, float& z, float& w, uint2 r) {
    x += __uint_as_float(r.x << 16); y += __uint_as_float(r.x & 0xffff0000u);
    z += __uint_as_float(r.y << 16); w += __uint_as_float(r.y & 0xffff0000u);
}

// ---------- zero bucketCur (replaces hipMemsetAsync: the runtime's
// fillBufferAligned ran at ~45µs/call for this 16KB buffer — R15 top-1) ----------
__global__ __launch_bounds__(1024) void zero_kernel(int4* __restrict__ p) {
    p[threadIdx.x] = make_int4(0, 0, 0, 0);   // 1024 x 16B = 16 KB
}

// ---------- mega: edge binning (phase A) + x->bf16 convert + W prepack ----------
// Phase A: LDS histogram per block -> ONE global atomicAdd per (block,bucket)
// (65K total vs 1M) -> packed writes, each (block,bucket) chunk ~= one 64B line.
// Convert/prepack blocks backfill CUs idle during the 256-block binning.
// bucketCur zeroed by zero_kernel BEFORE this launch.
__global__ __launch_bounds__(256) void mega_kernel(
    const int* __restrict__ src, const int* __restrict__ dst, int E4,
    int* __restrict__ bucketCur, unsigned* __restrict__ binned,
    const float4* __restrict__ xin, ushort4v* __restrict__ xb, int n4, int nbConv,
    const float* __restrict__ wl1, const float* __restrict__ wr1,
    const float* __restrict__ wl2, const float* __restrict__ wr2,
    const float* __restrict__ wl3, const float* __restrict__ wr3,
    unsigned short* __restrict__ WhAll, unsigned short* __restrict__ WloAll)
{
    const int tid = threadIdx.x;
    if ((int)blockIdx.x < NBINA) {
        __shared__ int hist[NBUCK];
        __shared__ int cur [NBUCK];
        __shared__ int base[NBUCK];
        hist[tid] = 0; cur[tid] = 0;
        __syncthreads();
        const int per = (E4 + NBINA - 1) / NBINA;       // 1024 int4
        const int t0 = blockIdx.x * per;
        const int te = min(t0 + per, E4);
        for (int it = t0 + tid; it < te; it += 256) {
            const i32x4 dv = *(((const i32x4*)dst) + it);
            #pragma unroll
            for (int j = 0; j < 4; ++j) atomicAdd(&hist[(unsigned)dv[j] >> 8], 1);
        }
        __syncthreads();
        {
            const int h = hist[tid];
            base[tid] = h ? atomicAdd(&bucketCur[tid * 16], h) : 0;
        }
        __syncthreads();
        for (int it = t0 + tid; it < te; it += 256) {
            const i32x4 dv = *(((const i32x4*)dst) + it);   // L2-hot re-read
            const i32x4 sv = *(((const i32x4*)src) + it);
            #pragma unroll
            for (int j = 0; j < 4; ++j) {
                const int b = (unsigned)dv[j] >> 8;
                const int p = atomicAdd(&cur[b], 1);        // LDS atomic (fast)
                const int pos = base[b] + p;
                if (pos < BCAP)
                    binned[(size_t)b * BCAP + pos] =
                        ((unsigned)sv[j] & 0xffffu) | (((unsigned)dv[j] & 255u) << 16);
            }
        }
        return;
    }
    if ((int)blockIdx.x < NBINA + nbConv) {
        const int t = ((int)blockIdx.x - NBINA) * 256 + tid;
        if (t < n4) {
            const float4 v = xin[t];
            ushort4v o;
            o[0] = f2bf(v.x); o[1] = f2bf(v.y); o[2] = f2bf(v.z); o[3] = f2bf(v.w);
            xb[t] = o;
        }
        return;
    }
    const int pb = (int)blockIdx.x - NBINA - nbConv;   // 0..11
    const int layer = pb >> 2;
    const float* Wl = (layer == 0) ? wl1 : (layer == 1) ? wl2 : wl3;
    const float* Wr = (layer == 0) ? wr1 : (layer == 1) ? wr2 : wr3;
    unsigned short* Wh  = WhAll  + layer * D * 128;
    unsigned short* Wlo = WloAll + layer * D * 128;
    const int p = (pb & 3) * 256 + tid;
    const int col = p >> 4, kc = p & 15;
    ushort8 hi, lo;
    #pragma unroll
    for (int j = 0; j < 8; ++j) {
        const int k = kc * 8 + j;
        const float f = (k < 64) ? Wl[k * 64 + col] : Wr[(k - 64) * 64 + col];
        const unsigned short h = f2bf(f);
        hi[j] = (short)h;
        lo[j] = (short)f2bf(f - bf2f(h));
    }
    *reinterpret_cast<ushort8*>(&Wh [col * 128 + kc * 8]) = hi;
    *reinterpret_cast<ushort8*>(&Wlo[col * 128 + kc * 8]) = lo;
}

// ---------- phase B: bucket -> ELL via LDS atomics ----------
// One block per bucket. Slot assignment via LDS atomicAdd (no global RMW);
// prim writes land in this block's EXCLUSIVE 16KB region. Exact degree
// written to cursor (no pre-zeroing).
__global__ __launch_bounds__(256) void binB_kernel(
    const unsigned* __restrict__ binned, const int* __restrict__ bucketCur,
    unsigned short* __restrict__ prim, unsigned short* __restrict__ ovfl,
    int* __restrict__ cursor)
{
    __shared__ int cnt[BNODE];
    const int tid = threadIdx.x;
    const int b = blockIdx.x;
    cnt[tid] = 0;
    __syncthreads();
    const int total = min(bucketCur[b * 16], BCAP);
    for (int i = tid; i < total; i += 256) {
        const unsigned e = binned[(size_t)b * BCAP + i];
        const int nl = (e >> 16) & 255;
        const unsigned short s = (unsigned short)(e & 0xffffu);
        const int p = atomicAdd(&cnt[nl], 1);              // LDS atomic
        const int node = b * BNODE + nl;
        if (p < PCAP)      prim[node * PCAP + p]          = s;
        else if (p < CAP)  ovfl[node * PCAP + (p - PCAP)] = s;
    }
    __syncthreads();
    cursor[b * BNODE + tid] = cnt[tid];
}

// ---------- gather-mean, straight-line 2-step, bf16 output (validated R13/R15) ----------
// Preload: lanes 0..31 = node A's 32-slot line, lanes 32..63 = node B's.
// Step guards are wave-uniform; every __shfl runs with all 64 lanes active
// (shfl from inactive lane is UB). Overflow (deg>32) is a rare uniform path.
__global__ __launch_bounds__(256) void gather_b(
    const unsigned short* __restrict__ tab, const unsigned short* __restrict__ prim,
    const unsigned short* __restrict__ ovfl, const int* __restrict__ cursor,
    unsigned short* __restrict__ aggb, int n)
{
    const int wave = threadIdx.x >> 6;
    const int lane = threadIdx.x & 63;
    const int g = lane >> 4;
    const int i = lane & 15;
    const int nodeA = blockIdx.x * 8 + wave * 2;
    const int nodeB = nodeA + 1;
    const int half = lane >> 5;
    const int slot = lane & 31;
    const int myNode = half ? nodeB : nodeA;
    int raw = prim[myNode * PCAP + slot];
    const int cA = cursor[nodeA];
    const int cB = cursor[nodeB];
    const int dA = min(cA, CAP), dB = min(cB, CAP);
    const int lim = half ? dB : dA;
    raw = (slot < lim) ? raw : 0;                  // sanitize beyond-degree
    const int maxd = max(dA, dB);

    float a0=0.f,a1=0.f,a2=0.f,a3=0.f;
    float b0=0.f,b1=0.f,b2=0.f,b3=0.f;

    auto step = [&](int r, int l0, int s0) {
        const int nA0 = __shfl(r, l0),      nA1 = __shfl(r, l0 + 4);
        const int nA2 = __shfl(r, l0 + 8),  nA3 = __shfl(r, l0 + 12);
        const int nB0 = __shfl(r, 32 + l0),     nB1 = __shfl(r, 32 + l0 + 4);
        const int nB2 = __shfl(r, 32 + l0 + 8), nB3 = __shfl(r, 32 + l0 + 12);
        const uint2 rA0 = *reinterpret_cast<const uint2*>(tab + (size_t)nA0 * D + i * 4);
        const uint2 rA1 = *reinterpret_cast<const uint2*>(tab + (size_t)nA1 * D + i * 4);
        const uint2 rA2 = *reinterpret_cast<const uint2*>(tab + (size_t)nA2 * D + i * 4);
        const uint2 rA3 = *reinterpret_cast<const uint2*>(tab + (size_t)nA3 * D + i * 4);
        const uint2 rB0 = *reinterpret_cast<const uint2*>(tab + (size_t)nB0 * D + i * 4);
        const uint2 rB1 = *reinterpret_cast<const uint2*>(tab + (size_t)nB1 * D + i * 4);
        const uint2 rB2 = *reinterpret_cast<const uint2*>(tab + (size_t)nB2 * D + i * 4);
        const uint2 rB3 = *reinterpret_cast<const uint2*>(tab + (size_t)nB3 * D + i * 4);
        if (s0      < dA) acc4(a0, a1, a2, a3, rA0);
        if (s0 + 4  < dA) acc4(a0, a1, a2, a3, rA1);
        if (s0 + 8  < dA) acc4(a0, a1, a2, a3, rA2);
        if (s0 + 12 < dA) acc4(a0, a1, a2, a3, rA3);
        if (s0      < dB) acc4(b0, b1, b2, b3, rB0);
        if (s0 + 4  < dB) acc4(b0, b1, b2, b3, rB1);
        if (s0 + 8  < dB) acc4(b0, b1, b2, b3, rB2);
        if (s0 + 12 < dB) acc4(b0, b1, b2, b3, rB3);
    };

    step(raw, g, g);                               // slots 0..15 (always)
    if (maxd > 16) step(raw, 16 + g, 16 + g);      // slots 16..31 (wave-uniform)
    if (maxd > PCAP) {                             // overflow, rare
        int ov = ovfl[myNode * PCAP + slot];
        ov = (PCAP + slot < lim) ? ov : 0;
        step(ov, g, 32 + g);
        if (maxd > 48) step(ov, 16 + g, 48 + g);
    }

    a0 += __shfl_xor(a0, 16); a1 += __shfl_xor(a1, 16);
    a2 += __shfl_xor(a2, 16); a3 += __shfl_xor(a3, 16);
    a0 += __shfl_xor(a0, 32); a1 += __shfl_xor(a1, 32);
    a2 += __shfl_xor(a2, 32); a3 += __shfl_xor(a3, 32);
    b0 += __shfl_xor(b0, 16); b1 += __shfl_xor(b1, 16);
    b2 += __shfl_xor(b2, 16); b3 += __shfl_xor(b3, 16);
    b0 += __shfl_xor(b0, 32); b1 += __shfl_xor(b1, 32);
    b2 += __shfl_xor(b2, 32); b3 += __shfl_xor(b3, 32);
    if (g == 0) {
        const float inv = 1.0f / fmaxf((float)cA, 1.0f);
        ushort4v o;
        o[0] = f2bf(a0 * inv); o[1] = f2bf(a1 * inv);
        o[2] = f2bf(a2 * inv); o[3] = f2bf(a3 * inv);
        *reinterpret_cast<ushort4v*>(aggb + (size_t)nodeA * D + i * 4) = o;
    } else if (g == 1) {
        const float inv = 1.0f / fmaxf((float)cB, 1.0f);
        ushort4v o;
        o[0] = f2bf(b0 * inv); o[1] = f2bf(b1 * inv);
        o[2] = f2bf(b2 * inv); o[3] = f2bf(b3 * inv);
        *reinterpret_cast<ushort4v*>(aggb + (size_t)nodeB * D + i * 4) = o;
    }
}

// ---------- MFMA GEMM: out[64 nodes][64] = [aggb | root][128] @ W + bias ----------
// A all-bf16 (aggb + root tables, pure LDS copies). W hi/lo split: 2 MFMA/chunk.
// C/D layout (HW-verified m89/m91): col=lane&15, row=(lane>>4)*4+reg.
// LDS XOR-swizzle: chunk_slot = chunk ^ (outer&7) (G4 bank-conflict fix).
template<bool RELU, bool BF16OUT>
__global__ __launch_bounds__(256) void gemm_mfma(
    const unsigned short* __restrict__ aggb, const unsigned short* __restrict__ root,
    const unsigned short* __restrict__ Wh, const unsigned short* __restrict__ Wlo,
    const float* __restrict__ bias, unsigned short* outb, float* outf)
{
    __shared__ unsigned short Ah[64 * 128];
    __shared__ unsigned short Bh[64 * 128];
    __shared__ unsigned short Bl[64 * 128];
    const int tid = threadIdx.x;
    const int node0 = blockIdx.x * 64;

    #pragma unroll
    for (int i = 0; i < 4; ++i) {
        const int p = i * 256 + tid;
        const int col = p >> 4, kc = p & 15;
        const int dst = col * 128 + ((kc ^ (col & 7)) << 3);
        *reinterpret_cast<ushort8*>(&Bh[dst]) =
            *reinterpret_cast<const ushort8*>(Wh + col * 128 + kc * 8);
        *reinterpret_cast<ushort8*>(&Bl[dst]) =
            *reinterpret_cast<const ushort8*>(Wlo + col * 128 + kc * 8);
    }
    #pragma unroll
    for (int i = 0; i < 4; ++i) {
        const int p = i * 256 + tid;
        const int node = p >> 4, kc = p & 15;
        const unsigned short* s = (kc < 8)
            ? aggb + (size_t)(node0 + node) * 64 + kc * 8
            : root + (size_t)(node0 + node) * 64 + (kc - 8) * 8;
        const int dst = node * 128 + ((kc ^ (node & 7)) << 3);
        *reinterpret_cast<ushort8*>(&Ah[dst]) =
            *reinterpret_cast<const ushort8*>(s);
    }
    __syncthreads();

    const int lane = tid & 63, w = tid >> 6;
    const int rl = lane & 15, g = lane >> 4;
    const int arow = w * 16 + rl;

    f32x4 acc[4];
    #pragma unroll
    for (int t = 0; t < 4; ++t) {
        const float b = bias[t * 16 + rl];
        acc[t] = (f32x4){b, b, b, b};
    }
    #pragma unroll
    for (int kc4 = 0; kc4 < 4; ++kc4) {
        const int c = kc4 * 4 + g;
        const int aoff = arow * 128 + ((c ^ (arow & 7)) << 3);
        const bf16x8 ah = *reinterpret_cast<const bf16x8*>(&Ah[aoff]);
        #pragma unroll
        for (int t = 0; t < 4; ++t) {
            const int bcol = t * 16 + rl;
            const int boff = bcol * 128 + ((c ^ (bcol & 7)) << 3);
            const bf16x8 bh = *reinterpret_cast<const bf16x8*>(&Bh[boff]);
            const bf16x8 bl = *reinterpret_cast<const bf16x8*>(&Bl[boff]);
            acc[t] = __builtin_amdgcn_mfma_f32_16x16x32_bf16(ah, bh, acc[t], 0, 0, 0);
            acc[t] = __builtin_amdgcn_mfma_f32_16x16x32_bf16(ah, bl, acc[t], 0, 0, 0);
        }
    }
    #pragma unroll
    for (int t = 0; t < 4; ++t) {
        #pragma unroll
        for (int r = 0; r < 4; ++r) {
            float v = acc[t][r];
            if (RELU) v = fmaxf(v, 0.0f);
            const size_t off = (size_t)(node0 + w * 16 + g * 4 + r) * 64 + t * 16 + rl;
            if (BF16OUT) outb[off] = f2bf(v);
            else         outf[off] = v;
        }
    }
}

extern "C" void kernel_launch(void* const* d_in, const int* in_sizes, int n_in,
                              void* d_out, int out_size, void* d_ws, size_t ws_size,
                              hipStream_t stream)
{
    const float* x    = (const float*)d_in[0];
    const int*   ei   = (const int*)d_in[1];
    const int    E    = in_sizes[1] / 2;     // 1,048,576
    const int*   src  = ei;
    const int*   dstp = ei + E;
    const float* wl1 = (const float*)d_in[2];
    const float* b1  = (const float*)d_in[3];
    const float* wr1 = (const float*)d_in[4];
    const float* wl2 = (const float*)d_in[5];
    const float* b2  = (const float*)d_in[6];
    const float* wr2 = (const float*)d_in[7];
    const float* wl3 = (const float*)d_in[8];
    const float* b3  = (const float*)d_in[9];
    const float* wr3 = (const float*)d_in[10];
    float* out = (float*)d_out;
    const int n = in_sizes[0] / D;           // 65536

    // workspace (~24.3 MiB):
    // prim 4M | ovfl 4M | cursor 256K | bucketCur 16K | W 96K |
    // union{ binned 4.6M (dead after binB) / aggb 8M } | hb2 8M
    unsigned short* prim = (unsigned short*)d_ws;
    unsigned short* ovfl = prim + (size_t)n * PCAP;
    int*   cursor    = (int*)(ovfl + (size_t)n * PCAP);
    int*   bucketCur = cursor + n;
    unsigned short* Wh  = (unsigned short*)(bucketCur + NBUCK * 16);
    unsigned short* Wlo = Wh + 3 * D * 128;
    unsigned short* aggb = Wlo + 3 * D * 128;            // union start
    unsigned* binned = (unsigned*)aggb;                  // aliased (binned dies first)
    unsigned short* hb2 = aggb + (size_t)n * D;          // after the 8M union

    // bf16 tables: xb = d_out half0 (dead after layer1), hb1 = d_out half1
    // (dead after layer2), hb2 in ws -> layer3 reads only ws, writes d_out fp32.
    unsigned short* xb  = (unsigned short*)d_out;
    unsigned short* hb1 = xb + (size_t)n * D;

    const int E4 = E / 4;
    const int nbConv = (n * 16) / 256;       // 4096

    zero_kernel<<<1, 1024, 0, stream>>>((int4*)bucketCur);
    mega_kernel<<<NBINA + nbConv + 12, 256, 0, stream>>>(
        src, dstp, E4, bucketCur, binned,
        (const float4*)x, (ushort4v*)xb, n * 16, nbConv,
        wl1, wr1, wl2, wr2, wl3, wr3, Wh, Wlo);
    binB_kernel<<<NBUCK, 256, 0, stream>>>(binned, bucketCur, prim, ovfl, cursor);

    const int gatherBlocks = n / 8;      // 2 nodes per wave, 32768 waves
    const int gemmBlocks   = n / 64;     // 1024

    // layer 1: xb -> hb1 (ReLU, bf16)
    gather_b<<<gatherBlocks, 256, 0, stream>>>(xb, prim, ovfl, cursor, aggb, n);
    gemm_mfma<true, true><<<gemmBlocks, 256, 0, stream>>>(
        aggb, xb, Wh, Wlo, b1, hb1, nullptr);

    // layer 2: hb1 -> hb2 (ReLU, bf16, into ws)
    gather_b<<<gatherBlocks, 256, 0, stream>>>(hb1, prim, ovfl, cursor, aggb, n);
    gemm_mfma<true, true><<<gemmBlocks, 256, 0, stream>>>(
        aggb, hb1, Wh + D * 128, Wlo + D * 128, b2, hb2, nullptr);

    // layer 3: hb2 -> d_out fp32 (reads only ws buffers)
    gather_b<<<gatherBlocks, 256, 0, stream>>>(hb2, prim, ovfl, cursor, aggb, n);
    gemm_mfma<false, false><<<gemmBlocks, 256, 0, stream>>>(
        aggb, hb2, Wh + 2 * D * 128, Wlo + 2 * D * 128, b3, nullptr, out);
}

// Round 17
// 113.270 us; speedup vs baseline: 1.0221x; 1.0221x over previous
//
#include <hip/hip_runtime.h>

constexpr int D     = 64;
constexpr int PCAP  = 32;    // primary ELL slots/node = one 64B line
constexpr int CAP   = 64;    // with overflow table; P(deg>64) ~ 0 (Poisson 16)
constexpr int NBUCK = 256;   // buckets (256 nodes each)
constexpr int BNODE = 256;   // nodes per bucket
constexpr int NBINA = 256;   // binning blocks in mega
constexpr int SCAP  = 48;    // per-(bucket,block) cell capacity: Poisson(16)+8sigma

typedef __attribute__((ext_vector_type(8))) short          bf16x8;
typedef __attribute__((ext_vector_type(4))) float          f32x4;
typedef __attribute__((ext_vector_type(8))) unsigned short ushort8;
typedef __attribute__((ext_vector_type(4))) unsigned short ushort4v;
typedef __attribute__((ext_vector_type(4))) int            i32x4;

__device__ __forceinline__ unsigned short f2bf(float f) {   // RTN fp32 -> bf16
    unsigned int u = __float_as_uint(f);
    u += 0x7FFFu + ((u >> 16) & 1u);
    return (unsigned short)(u >> 16);
}
__device__ __forceinline__ float bf2f(unsigned short h) {
    return __uint_as_float(((unsigned int)h) << 16);
}
__device__ __forceinline__ void acc4(float& x, float& y, float& z, float& w, uint2 r) {
    x += __uint_as_float(r.x << 16); y += __uint_as_float(r.x & 0xffff0000u);
    z += __uint_as_float(r.y << 16); w += __uint_as_float(r.y & 0xffff0000u);
}

// ---------- mega: single-pass edge binning + x->bf16 convert + W prepack ----------
// Phase A (blocks 0..NBINA-1): each block bins its E/256 edge chunk into
// fixed-capacity cells binned[bucket][block][SCAP] via LDS cursors — NO global
// atomics, NO counter pre-zeroing, ONE pass (R15 needed histogram+scatter).
// cnts[bucket][block] written unconditionally at the end.
// Convert/prepack blocks backfill CUs idle during binning.
__global__ __launch_bounds__(256) void mega_kernel(
    const int* __restrict__ src, const int* __restrict__ dst, int E4,
    unsigned* __restrict__ binned, int* __restrict__ cnts,
    const float4* __restrict__ xin, ushort4v* __restrict__ xb, int n4, int nbConv,
    const float* __restrict__ wl1, const float* __restrict__ wr1,
    const float* __restrict__ wl2, const float* __restrict__ wr2,
    const float* __restrict__ wl3, const float* __restrict__ wr3,
    unsigned short* __restrict__ WhAll, unsigned short* __restrict__ WloAll)
{
    const int tid = threadIdx.x;
    if ((int)blockIdx.x < NBINA) {
        __shared__ int cur[NBUCK];
        cur[tid] = 0;
        __syncthreads();
        const int per = E4 / NBINA;                  // 1024 int4 per block
        const int t0 = blockIdx.x * per;
        const int te = t0 + per;
        for (int it = t0 + tid; it < te; it += 256) {
            const i32x4 dv = *(((const i32x4*)dst) + it);
            const i32x4 sv = *(((const i32x4*)src) + it);
            #pragma unroll
            for (int j = 0; j < 4; ++j) {
                const int b = (unsigned)dv[j] >> 8;
                const int p = atomicAdd(&cur[b], 1);         // LDS atomic
                if (p < SCAP)
                    binned[((size_t)b * NBINA + blockIdx.x) * SCAP + p] =
                        ((unsigned)sv[j] & 0xffffu) | (((unsigned)dv[j] & 255u) << 16);
            }
        }
        __syncthreads();
        cnts[tid * NBINA + blockIdx.x] = min(cur[tid], SCAP);
        return;
    }
    if ((int)blockIdx.x < NBINA + nbConv) {
        const int t = ((int)blockIdx.x - NBINA) * 256 + tid;
        if (t < n4) {
            const float4 v = xin[t];
            ushort4v o;
            o[0] = f2bf(v.x); o[1] = f2bf(v.y); o[2] = f2bf(v.z); o[3] = f2bf(v.w);
            xb[t] = o;
        }
        return;
    }
    const int pb = (int)blockIdx.x - NBINA - nbConv;   // 0..11
    const int layer = pb >> 2;
    const float* Wl = (layer == 0) ? wl1 : (layer == 1) ? wl2 : wl3;
    const float* Wr = (layer == 0) ? wr1 : (layer == 1) ? wr2 : wr3;
    unsigned short* Wh  = WhAll  + layer * D * 128;
    unsigned short* Wlo = WloAll + layer * D * 128;
    const int p = (pb & 3) * 256 + tid;
    const int col = p >> 4, kc = p & 15;
    ushort8 hi, lo;
    #pragma unroll
    for (int j = 0; j < 8; ++j) {
        const int k = kc * 8 + j;
        const float f = (k < 64) ? Wl[k * 64 + col] : Wr[(k - 64) * 64 + col];
        const unsigned short h = f2bf(f);
        hi[j] = (short)h;
        lo[j] = (short)f2bf(f - bf2f(h));
    }
    *reinterpret_cast<ushort8*>(&Wh [col * 128 + kc * 8]) = hi;
    *reinterpret_cast<ushort8*>(&Wlo[col * 128 + kc * 8]) = lo;
}

// ---------- phase B: bucket -> ELL via LDS atomics ----------
// One block per bucket b; thread t walks cell (b, t) sequentially (line-local
// reads; cnts read is coalesced). Slot assignment via LDS atomicAdd; prim
// writes land in this block's EXCLUSIVE 16KB region. Exact degree -> cursor.
__global__ __launch_bounds__(256) void binB_kernel(
    const unsigned* __restrict__ binned, const int* __restrict__ cnts,
    unsigned short* __restrict__ prim, unsigned short* __restrict__ ovfl,
    int* __restrict__ cursor)
{
    __shared__ int cnt[BNODE];
    const int tid = threadIdx.x;
    const int b = blockIdx.x;
    cnt[tid] = 0;
    __syncthreads();
    const int c = cnts[b * NBINA + tid];
    const unsigned* cell = binned + ((size_t)b * NBINA + tid) * SCAP;
    for (int p = 0; p < c; ++p) {
        const unsigned e = cell[p];
        const int nl = (e >> 16) & 255;
        const unsigned short s = (unsigned short)(e & 0xffffu);
        const int q = atomicAdd(&cnt[nl], 1);              // LDS atomic
        const int node = b * BNODE + nl;
        if (q < PCAP)      prim[node * PCAP + q]          = s;
        else if (q < CAP)  ovfl[node * PCAP + (q - PCAP)] = s;
    }
    __syncthreads();
    cursor[b * BNODE + tid] = cnt[tid];
}

// ---------- gather-mean, straight-line UNCONDITIONAL 2-step, bf16 output ----------
// Preload: lanes 0..31 = node A's 32-slot line, lanes 32..63 = node B's.
// Both steps always execute (R16 change: ~68% of pairs took the second
// DEPENDENT round under the maxd>16 guard; unconditional makes all 32
// row-loads independent -> one latency round). Wasted loads for deg<=16 hit
// sanitized row 0 (L1-hot). Every __shfl runs with all 64 lanes active
// (shfl from inactive lane is UB). Overflow (deg>32) is a rare uniform path.
__global__ __launch_bounds__(256) void gather_b(
    const unsigned short* __restrict__ tab, const unsigned short* __restrict__ prim,
    const unsigned short* __restrict__ ovfl, const int* __restrict__ cursor,
    unsigned short* __restrict__ aggb, int n)
{
    const int wave = threadIdx.x >> 6;
    const int lane = threadIdx.x & 63;
    const int g = lane >> 4;
    const int i = lane & 15;
    const int nodeA = blockIdx.x * 8 + wave * 2;
    const int nodeB = nodeA + 1;
    const int half = lane >> 5;
    const int slot = lane & 31;
    const int myNode = half ? nodeB : nodeA;
    int raw = prim[myNode * PCAP + slot];
    const int cA = cursor[nodeA];
    const int cB = cursor[nodeB];
    const int dA = min(cA, CAP), dB = min(cB, CAP);
    const int lim = half ? dB : dA;
    raw = (slot < lim) ? raw : 0;                  // sanitize beyond-degree
    const int maxd = max(dA, dB);

    float a0=0.f,a1=0.f,a2=0.f,a3=0.f;
    float b0=0.f,b1=0.f,b2=0.f,b3=0.f;

    auto step = [&](int r, int l0, int s0) {
        const int nA0 = __shfl(r, l0),      nA1 = __shfl(r, l0 + 4);
        const int nA2 = __shfl(r, l0 + 8),  nA3 = __shfl(r, l0 + 12);
        const int nB0 = __shfl(r, 32 + l0),     nB1 = __shfl(r, 32 + l0 + 4);
        const int nB2 = __shfl(r, 32 + l0 + 8), nB3 = __shfl(r, 32 + l0 + 12);
        const uint2 rA0 = *reinterpret_cast<const uint2*>(tab + (size_t)nA0 * D + i * 4);
        const uint2 rA1 = *reinterpret_cast<const uint2*>(tab + (size_t)nA1 * D + i * 4);
        const uint2 rA2 = *reinterpret_cast<const uint2*>(tab + (size_t)nA2 * D + i * 4);
        const uint2 rA3 = *reinterpret_cast<const uint2*>(tab + (size_t)nA3 * D + i * 4);
        const uint2 rB0 = *reinterpret_cast<const uint2*>(tab + (size_t)nB0 * D + i * 4);
        const uint2 rB1 = *reinterpret_cast<const uint2*>(tab + (size_t)nB1 * D + i * 4);
        const uint2 rB2 = *reinterpret_cast<const uint2*>(tab + (size_t)nB2 * D + i * 4);
        const uint2 rB3 = *reinterpret_cast<const uint2*>(tab + (size_t)nB3 * D + i * 4);
        if (s0      < dA) acc4(a0, a1, a2, a3, rA0);
        if (s0 + 4  < dA) acc4(a0, a1, a2, a3, rA1);
        if (s0 + 8  < dA) acc4(a0, a1, a2, a3, rA2);
        if (s0 + 12 < dA) acc4(a0, a1, a2, a3, rA3);
        if (s0      < dB) acc4(b0, b1, b2, b3, rB0);
        if (s0 + 4  < dB) acc4(b0, b1, b2, b3, rB1);
        if (s0 + 8  < dB) acc4(b0, b1, b2, b3, rB2);
        if (s0 + 12 < dB) acc4(b0, b1, b2, b3, rB3);
    };

    step(raw, g, g);                 // slots 0..15
    step(raw, 16 + g, 16 + g);       // slots 16..31 (unconditional)
    if (maxd > PCAP) {               // overflow, rare (~3e-5 of nodes)
        int ov = ovfl[myNode * PCAP + slot];
        ov = (PCAP + slot < lim) ? ov : 0;
        step(ov, g, 32 + g);
        if (maxd > 48) step(ov, 16 + g, 48 + g);
    }

    a0 += __shfl_xor(a0, 16); a1 += __shfl_xor(a1, 16);
    a2 += __shfl_xor(a2, 16); a3 += __shfl_xor(a3, 16);
    a0 += __shfl_xor(a0, 32); a1 += __shfl_xor(a1, 32);
    a2 += __shfl_xor(a2, 32); a3 += __shfl_xor(a3, 32);
    b0 += __shfl_xor(b0, 16); b1 += __shfl_xor(b1, 16);
    b2 += __shfl_xor(b2, 16); b3 += __shfl_xor(b3, 16);
    b0 += __shfl_xor(b0, 32); b1 += __shfl_xor(b1, 32);
    b2 += __shfl_xor(b2, 32); b3 += __shfl_xor(b3, 32);
    if (g == 0) {
        const float inv = 1.0f / fmaxf((float)cA, 1.0f);
        ushort4v o;
        o[0] = f2bf(a0 * inv); o[1] = f2bf(a1 * inv);
        o[2] = f2bf(a2 * inv); o[3] = f2bf(a3 * inv);
        *reinterpret_cast<ushort4v*>(aggb + (size_t)nodeA * D + i * 4) = o;
    } else if (g == 1) {
        const float inv = 1.0f / fmaxf((float)cB, 1.0f);
        ushort4v o;
        o[0] = f2bf(b0 * inv); o[1] = f2bf(b1 * inv);
        o[2] = f2bf(b2 * inv); o[3] = f2bf(b3 * inv);
        *reinterpret_cast<ushort4v*>(aggb + (size_t)nodeB * D + i * 4) = o;
    }
}

// ---------- MFMA GEMM: out[64 nodes][64] = [aggb | root][128] @ W + bias ----------
// A all-bf16 (aggb + root tables, pure LDS copies). W hi/lo split: 2 MFMA/chunk.
// C/D layout (HW-verified m89/m91): col=lane&15, row=(lane>>4)*4+reg.
// LDS XOR-swizzle: chunk_slot = chunk ^ (outer&7) (G4 bank-conflict fix).
template<bool RELU, bool BF16OUT>
__global__ __launch_bounds__(256) void gemm_mfma(
    const unsigned short* __restrict__ aggb, const unsigned short* __restrict__ root,
    const unsigned short* __restrict__ Wh, const unsigned short* __restrict__ Wlo,
    const float* __restrict__ bias, unsigned short* outb, float* outf)
{
    __shared__ unsigned short Ah[64 * 128];
    __shared__ unsigned short Bh[64 * 128];
    __shared__ unsigned short Bl[64 * 128];
    const int tid = threadIdx.x;
    const int node0 = blockIdx.x * 64;

    #pragma unroll
    for (int i = 0; i < 4; ++i) {
        const int p = i * 256 + tid;
        const int col = p >> 4, kc = p & 15;
        const int dst = col * 128 + ((kc ^ (col & 7)) << 3);
        *reinterpret_cast<ushort8*>(&Bh[dst]) =
            *reinterpret_cast<const ushort8*>(Wh + col * 128 + kc * 8);
        *reinterpret_cast<ushort8*>(&Bl[dst]) =
            *reinterpret_cast<const ushort8*>(Wlo + col * 128 + kc * 8);
    }
    #pragma unroll
    for (int i = 0; i < 4; ++i) {
        const int p = i * 256 + tid;
        const int node = p >> 4, kc = p & 15;
        const unsigned short* s = (kc < 8)
            ? aggb + (size_t)(node0 + node) * 64 + kc * 8
            : root + (size_t)(node0 + node) * 64 + (kc - 8) * 8;
        const int dst = node * 128 + ((kc ^ (node & 7)) << 3);
        *reinterpret_cast<ushort8*>(&Ah[dst]) =
            *reinterpret_cast<const ushort8*>(s);
    }
    __syncthreads();

    const int lane = tid & 63, w = tid >> 6;
    const int rl = lane & 15, g = lane >> 4;
    const int arow = w * 16 + rl;

    f32x4 acc[4];
    #pragma unroll
    for (int t = 0; t < 4; ++t) {
        const float b = bias[t * 16 + rl];
        acc[t] = (f32x4){b, b, b, b};
    }
    #pragma unroll
    for (int kc4 = 0; kc4 < 4; ++kc4) {
        const int c = kc4 * 4 + g;
        const int aoff = arow * 128 + ((c ^ (arow & 7)) << 3);
        const bf16x8 ah = *reinterpret_cast<const bf16x8*>(&Ah[aoff]);
        #pragma unroll
        for (int t = 0; t < 4; ++t) {
            const int bcol = t * 16 + rl;
            const int boff = bcol * 128 + ((c ^ (bcol & 7)) << 3);
            const bf16x8 bh = *reinterpret_cast<const bf16x8*>(&Bh[boff]);
            const bf16x8 bl = *reinterpret_cast<const bf16x8*>(&Bl[boff]);
            acc[t] = __builtin_amdgcn_mfma_f32_16x16x32_bf16(ah, bh, acc[t], 0, 0, 0);
            acc[t] = __builtin_amdgcn_mfma_f32_16x16x32_bf16(ah, bl, acc[t], 0, 0, 0);
        }
    }
    #pragma unroll
    for (int t = 0; t < 4; ++t) {
        #pragma unroll
        for (int r = 0; r < 4; ++r) {
            float v = acc[t][r];
            if (RELU) v = fmaxf(v, 0.0f);
            const size_t off = (size_t)(node0 + w * 16 + g * 4 + r) * 64 + t * 16 + rl;
            if (BF16OUT) outb[off] = f2bf(v);
            else         outf[off] = v;
        }
    }
}

extern "C" void kernel_launch(void* const* d_in, const int* in_sizes, int n_in,
                              void* d_out, int out_size, void* d_ws, size_t ws_size,
                              hipStream_t stream)
{
    const float* x    = (const float*)d_in[0];
    const int*   ei   = (const int*)d_in[1];
    const int    E    = in_sizes[1] / 2;     // 1,048,576
    const int*   src  = ei;
    const int*   dstp = ei + E;
    const float* wl1 = (const float*)d_in[2];
    const float* b1  = (const float*)d_in[3];
    const float* wr1 = (const float*)d_in[4];
    const float* wl2 = (const float*)d_in[5];
    const float* b2  = (const float*)d_in[6];
    const float* wr2 = (const float*)d_in[7];
    const float* wl3 = (const float*)d_in[8];
    const float* b3  = (const float*)d_in[9];
    const float* wr3 = (const float*)d_in[10];
    float* out = (float*)d_out;
    const int n = in_sizes[0] / D;           // 65536

    // workspace (~24.6 MiB):
    // prim 4M | ovfl 4M | cursor 256K | cnts 256K | W 96K |
    // unionArea 16M = { binned 12.6M (dead after binB) / aggb 8M + hb2 8M }
    unsigned short* prim = (unsigned short*)d_ws;
    unsigned short* ovfl = prim + (size_t)n * PCAP;
    int*   cursor = (int*)(ovfl + (size_t)n * PCAP);
    int*   cnts   = cursor + n;
    unsigned short* Wh  = (unsigned short*)(cnts + NBUCK * NBINA);
    unsigned short* Wlo = Wh + 3 * D * 128;
    unsigned short* aggb = Wlo + 3 * D * 128;            // union start
    unsigned* binned = (unsigned*)aggb;                  // aliased (dies at binB end)
    unsigned short* hb2 = aggb + (size_t)n * D;

    // bf16 tables: xb = d_out half0 (dead after layer1), hb1 = d_out half1
    // (dead after layer2), hb2 in ws -> layer3 reads only ws, writes d_out fp32.
    unsigned short* xb  = (unsigned short*)d_out;
    unsigned short* hb1 = xb + (size_t)n * D;

    const int E4 = E / 4;
    const int nbConv = (n * 16) / 256;       // 4096

    mega_kernel<<<NBINA + nbConv + 12, 256, 0, stream>>>(
        src, dstp, E4, binned, cnts,
        (const float4*)x, (ushort4v*)xb, n * 16, nbConv,
        wl1, wr1, wl2, wr2, wl3, wr3, Wh, Wlo);
    binB_kernel<<<NBUCK, 256, 0, stream>>>(binned, cnts, prim, ovfl, cursor);

    const int gatherBlocks = n / 8;      // 2 nodes per wave, 32768 waves
    const int gemmBlocks   = n / 64;     // 1024

    // layer 1: xb -> hb1 (ReLU, bf16)
    gather_b<<<gatherBlocks, 256, 0, stream>>>(xb, prim, ovfl, cursor, aggb, n);
    gemm_mfma<true, true><<<gemmBlocks, 256, 0, stream>>>(
        aggb, xb, Wh, Wlo, b1, hb1, nullptr);

    // layer 2: hb1 -> hb2 (ReLU, bf16, into ws)
    gather_b<<<gatherBlocks, 256, 0, stream>>>(hb1, prim, ovfl, cursor, aggb, n);
    gemm_mfma<true, true><<<gemmBlocks, 256, 0, stream>>>(
        aggb, hb1, Wh + D * 128, Wlo + D * 128, b2, hb2, nullptr);

    // layer 3: hb2 -> d_out fp32 (reads only ws buffers)
    gather_b<<<gatherBlocks, 256, 0, stream>>>(hb2, prim, ovfl, cursor, aggb, n);
    gemm_mfma<false, false><<<gemmBlocks, 256, 0, stream>>>(
        aggb, hb2, Wh + 2 * D * 128, Wlo + 2 * D * 128, b3, nullptr, out);
}

// Round 18
// 109.561 us; speedup vs baseline: 1.0567x; 1.0338x over previous
//
#include <hip/hip_runtime.h>

constexpr int D     = 64;
constexpr int PCAP  = 32;    // primary ELL slots/node = one 64B line
constexpr int CAP   = 64;    // with overflow table; P(deg>64) ~ 0 (Poisson 16)
constexpr int NBUCK = 256;   // buckets (256 nodes each)
constexpr int BNODE = 256;   // nodes per bucket
constexpr int NBINA = 256;   // binning blocks in mega
constexpr int SCAP  = 48;    // per-(bucket,block) cell capacity: Poisson(16)+8sigma

typedef __attribute__((ext_vector_type(8))) short          bf16x8;
typedef __attribute__((ext_vector_type(4))) float          f32x4;
typedef __attribute__((ext_vector_type(8))) unsigned short ushort8;
typedef __attribute__((ext_vector_type(4))) unsigned short ushort4v;
typedef __attribute__((ext_vector_type(4))) int            i32x4;

__device__ __forceinline__ unsigned short f2bf(float f) {   // RTN fp32 -> bf16
    unsigned int u = __float_as_uint(f);
    u += 0x7FFFu + ((u >> 16) & 1u);
    return (unsigned short)(u >> 16);
}
__device__ __forceinline__ void acc4(float& x, float& y, float& z, float& w, uint2 r) {
    x += __uint_as_float(r.x << 16); y += __uint_as_float(r.x & 0xffff0000u);
    z += __uint_as_float(r.y << 16); w += __uint_as_float(r.y & 0xffff0000u);
}

// ---------- mega: single-pass edge binning + x->bf16 convert + W prepack ----------
// Phase A (blocks 0..NBINA-1): each block bins its E/256 edge chunk into
// fixed-capacity cells binned[bucket][block][SCAP] via LDS cursors — no global
// atomics, no counter pre-zeroing, one pass. cnts written unconditionally.
// Convert/prepack blocks backfill CUs idle during binning.
// R18: weights are pure bf16 now (Wlo dropped — error budget: +~4e-3 absmax,
// under the 1.68e-2 threshold with ~2x margin).
__global__ __launch_bounds__(256) void mega_kernel(
    const int* __restrict__ src, const int* __restrict__ dst, int E4,
    unsigned* __restrict__ binned, int* __restrict__ cnts,
    const float4* __restrict__ xin, ushort4v* __restrict__ xb, int n4, int nbConv,
    const float* __restrict__ wl1, const float* __restrict__ wr1,
    const float* __restrict__ wl2, const float* __restrict__ wr2,
    const float* __restrict__ wl3, const float* __restrict__ wr3,
    unsigned short* __restrict__ WhAll)
{
    const int tid = threadIdx.x;
    if ((int)blockIdx.x < NBINA) {
        __shared__ int cur[NBUCK];
        cur[tid] = 0;
        __syncthreads();
        const int per = E4 / NBINA;                  // 1024 int4 per block
        const int t0 = blockIdx.x * per;
        const int te = t0 + per;
        for (int it = t0 + tid; it < te; it += 256) {
            const i32x4 dv = *(((const i32x4*)dst) + it);
            const i32x4 sv = *(((const i32x4*)src) + it);
            #pragma unroll
            for (int j = 0; j < 4; ++j) {
                const int b = (unsigned)dv[j] >> 8;
                const int p = atomicAdd(&cur[b], 1);         // LDS atomic
                if (p < SCAP)
                    binned[((size_t)b * NBINA + blockIdx.x) * SCAP + p] =
                        ((unsigned)sv[j] & 0xffffu) | (((unsigned)dv[j] & 255u) << 16);
            }
        }
        __syncthreads();
        cnts[tid * NBINA + blockIdx.x] = min(cur[tid], SCAP);
        return;
    }
    if ((int)blockIdx.x < NBINA + nbConv) {
        const int t = ((int)blockIdx.x - NBINA) * 256 + tid;
        if (t < n4) {
            const float4 v = xin[t];
            ushort4v o;
            o[0] = f2bf(v.x); o[1] = f2bf(v.y); o[2] = f2bf(v.z); o[3] = f2bf(v.w);
            xb[t] = o;
        }
        return;
    }
    const int pb = (int)blockIdx.x - NBINA - nbConv;   // 0..11
    const int layer = pb >> 2;
    const float* Wl = (layer == 0) ? wl1 : (layer == 1) ? wl2 : wl3;
    const float* Wr = (layer == 0) ? wr1 : (layer == 1) ? wr2 : wr3;
    unsigned short* Wh = WhAll + layer * D * 128;
    const int p = (pb & 3) * 256 + tid;
    const int col = p >> 4, kc = p & 15;
    ushort8 hi;
    #pragma unroll
    for (int j = 0; j < 8; ++j) {
        const int k = kc * 8 + j;
        const float f = (k < 64) ? Wl[k * 64 + col] : Wr[(k - 64) * 64 + col];
        hi[j] = (short)f2bf(f);
    }
    *reinterpret_cast<ushort8*>(&Wh[col * 128 + kc * 8]) = hi;
}

// ---------- phase B: bucket -> ELL via LDS atomics ----------
// One block per bucket b; thread t walks cell (b, t) sequentially (line-local
// reads; cnts read is coalesced). Slot assignment via LDS atomicAdd; prim
// writes land in this block's EXCLUSIVE 16KB region. Exact degree -> cursor.
__global__ __launch_bounds__(256) void binB_kernel(
    const unsigned* __restrict__ binned, const int* __restrict__ cnts,
    unsigned short* __restrict__ prim, unsigned short* __restrict__ ovfl,
    int* __restrict__ cursor)
{
    __shared__ int cnt[BNODE];
    const int tid = threadIdx.x;
    const int b = blockIdx.x;
    cnt[tid] = 0;
    __syncthreads();
    const int c = cnts[b * NBINA + tid];
    const unsigned* cell = binned + ((size_t)b * NBINA + tid) * SCAP;
    for (int p = 0; p < c; ++p) {
        const unsigned e = cell[p];
        const int nl = (e >> 16) & 255;
        const unsigned short s = (unsigned short)(e & 0xffffu);
        const int q = atomicAdd(&cnt[nl], 1);              // LDS atomic
        const int node = b * BNODE + nl;
        if (q < PCAP)      prim[node * PCAP + q]          = s;
        else if (q < CAP)  ovfl[node * PCAP + (q - PCAP)] = s;
    }
    __syncthreads();
    cursor[b * BNODE + tid] = cnt[tid];
}

// ---------- gather-mean, straight-line unconditional 2-step, bf16 output ----------
// Preload: lanes 0..31 = node A's 32-slot line, lanes 32..63 = node B's.
// Both steps always execute (all 32 row-loads independent -> one latency
// round; waste loads hit sanitized row 0, L1-hot). Every __shfl runs with all
// 64 lanes active (shfl from inactive lane is UB). Overflow (deg>32) is a
// rare wave-uniform path. Validated R13-R17.
__global__ __launch_bounds__(256) void gather_b(
    const unsigned short* __restrict__ tab, const unsigned short* __restrict__ prim,
    const unsigned short* __restrict__ ovfl, const int* __restrict__ cursor,
    unsigned short* __restrict__ aggb, int n)
{
    const int wave = threadIdx.x >> 6;
    const int lane = threadIdx.x & 63;
    const int g = lane >> 4;
    const int i = lane & 15;
    const int nodeA = blockIdx.x * 8 + wave * 2;
    const int nodeB = nodeA + 1;
    const int half = lane >> 5;
    const int slot = lane & 31;
    const int myNode = half ? nodeB : nodeA;
    int raw = prim[myNode * PCAP + slot];
    const int cA = cursor[nodeA];
    const int cB = cursor[nodeB];
    const int dA = min(cA, CAP), dB = min(cB, CAP);
    const int lim = half ? dB : dA;
    raw = (slot < lim) ? raw : 0;                  // sanitize beyond-degree
    const int maxd = max(dA, dB);

    float a0=0.f,a1=0.f,a2=0.f,a3=0.f;
    float b0=0.f,b1=0.f,b2=0.f,b3=0.f;

    auto step = [&](int r, int l0, int s0) {
        const int nA0 = __shfl(r, l0),      nA1 = __shfl(r, l0 + 4);
        const int nA2 = __shfl(r, l0 + 8),  nA3 = __shfl(r, l0 + 12);
        const int nB0 = __shfl(r, 32 + l0),     nB1 = __shfl(r, 32 + l0 + 4);
        const int nB2 = __shfl(r, 32 + l0 + 8), nB3 = __shfl(r, 32 + l0 + 12);
        const uint2 rA0 = *reinterpret_cast<const uint2*>(tab + (size_t)nA0 * D + i * 4);
        const uint2 rA1 = *reinterpret_cast<const uint2*>(tab + (size_t)nA1 * D + i * 4);
        const uint2 rA2 = *reinterpret_cast<const uint2*>(tab + (size_t)nA2 * D + i * 4);
        const uint2 rA3 = *reinterpret_cast<const uint2*>(tab + (size_t)nA3 * D + i * 4);
        const uint2 rB0 = *reinterpret_cast<const uint2*>(tab + (size_t)nB0 * D + i * 4);
        const uint2 rB1 = *reinterpret_cast<const uint2*>(tab + (size_t)nB1 * D + i * 4);
        const uint2 rB2 = *reinterpret_cast<const uint2*>(tab + (size_t)nB2 * D + i * 4);
        const uint2 rB3 = *reinterpret_cast<const uint2*>(tab + (size_t)nB3 * D + i * 4);
        if (s0      < dA) acc4(a0, a1, a2, a3, rA0);
        if (s0 + 4  < dA) acc4(a0, a1, a2, a3, rA1);
        if (s0 + 8  < dA) acc4(a0, a1, a2, a3, rA2);
        if (s0 + 12 < dA) acc4(a0, a1, a2, a3, rA3);
        if (s0      < dB) acc4(b0, b1, b2, b3, rB0);
        if (s0 + 4  < dB) acc4(b0, b1, b2, b3, rB1);
        if (s0 + 8  < dB) acc4(b0, b1, b2, b3, rB2);
        if (s0 + 12 < dB) acc4(b0, b1, b2, b3, rB3);
    };

    step(raw, g, g);                 // slots 0..15
    step(raw, 16 + g, 16 + g);       // slots 16..31 (unconditional)
    if (maxd > PCAP) {               // overflow, rare (~3e-5 of nodes)
        int ov = ovfl[myNode * PCAP + slot];
        ov = (PCAP + slot < lim) ? ov : 0;
        step(ov, g, 32 + g);
        if (maxd > 48) step(ov, 16 + g, 48 + g);
    }

    a0 += __shfl_xor(a0, 16); a1 += __shfl_xor(a1, 16);
    a2 += __shfl_xor(a2, 16); a3 += __shfl_xor(a3, 16);
    a0 += __shfl_xor(a0, 32); a1 += __shfl_xor(a1, 32);
    a2 += __shfl_xor(a2, 32); a3 += __shfl_xor(a3, 32);
    b0 += __shfl_xor(b0, 16); b1 += __shfl_xor(b1, 16);
    b2 += __shfl_xor(b2, 16); b3 += __shfl_xor(b3, 16);
    b0 += __shfl_xor(b0, 32); b1 += __shfl_xor(b1, 32);
    b2 += __shfl_xor(b2, 32); b3 += __shfl_xor(b3, 32);
    if (g == 0) {
        const float inv = 1.0f / fmaxf((float)cA, 1.0f);
        ushort4v o;
        o[0] = f2bf(a0 * inv); o[1] = f2bf(a1 * inv);
        o[2] = f2bf(a2 * inv); o[3] = f2bf(a3 * inv);
        *reinterpret_cast<ushort4v*>(aggb + (size_t)nodeA * D + i * 4) = o;
    } else if (g == 1) {
        const float inv = 1.0f / fmaxf((float)cB, 1.0f);
        ushort4v o;
        o[0] = f2bf(b0 * inv); o[1] = f2bf(b1 * inv);
        o[2] = f2bf(b2 * inv); o[3] = f2bf(b3 * inv);
        *reinterpret_cast<ushort4v*>(aggb + (size_t)nodeB * D + i * 4) = o;
    }
}

// ---------- MFMA GEMM: out[64 nodes][64] = [aggb | root][128] @ Wh + bias ----------
// All-bf16 A and W (R18: Wlo dropped -> 16 MFMA/thread, 32 KB LDS, 5 blocks/CU
// by LDS). C/D layout (HW-verified m89/m91): col=lane&15, row=(lane>>4)*4+reg.
// LDS XOR-swizzle: chunk_slot = chunk ^ (outer&7) (G4 bank-conflict fix).
template<bool RELU, bool BF16OUT>
__global__ __launch_bounds__(256) void gemm_mfma(
    const unsigned short* __restrict__ aggb, const unsigned short* __restrict__ root,
    const unsigned short* __restrict__ Wh,
    const float* __restrict__ bias, unsigned short* outb, float* outf)
{
    __shared__ unsigned short Ah[64 * 128];
    __shared__ unsigned short Bh[64 * 128];
    const int tid = threadIdx.x;
    const int node0 = blockIdx.x * 64;

    #pragma unroll
    for (int i = 0; i < 4; ++i) {
        const int p = i * 256 + tid;
        const int col = p >> 4, kc = p & 15;
        const int dst = col * 128 + ((kc ^ (col & 7)) << 3);
        *reinterpret_cast<ushort8*>(&Bh[dst]) =
            *reinterpret_cast<const ushort8*>(Wh + col * 128 + kc * 8);
    }
    #pragma unroll
    for (int i = 0; i < 4; ++i) {
        const int p = i * 256 + tid;
        const int node = p >> 4, kc = p & 15;
        const unsigned short* s = (kc < 8)
            ? aggb + (size_t)(node0 + node) * 64 + kc * 8
            : root + (size_t)(node0 + node) * 64 + (kc - 8) * 8;
        const int dst = node * 128 + ((kc ^ (node & 7)) << 3);
        *reinterpret_cast<ushort8*>(&Ah[dst]) =
            *reinterpret_cast<const ushort8*>(s);
    }
    __syncthreads();

    const int lane = tid & 63, w = tid >> 6;
    const int rl = lane & 15, g = lane >> 4;
    const int arow = w * 16 + rl;

    f32x4 acc[4];
    #pragma unroll
    for (int t = 0; t < 4; ++t) {
        const float b = bias[t * 16 + rl];
        acc[t] = (f32x4){b, b, b, b};
    }
    #pragma unroll
    for (int kc4 = 0; kc4 < 4; ++kc4) {
        const int c = kc4 * 4 + g;
        const int aoff = arow * 128 + ((c ^ (arow & 7)) << 3);
        const bf16x8 ah = *reinterpret_cast<const bf16x8*>(&Ah[aoff]);
        #pragma unroll
        for (int t = 0; t < 4; ++t) {
            const int bcol = t * 16 + rl;
            const int boff = bcol * 128 + ((c ^ (bcol & 7)) << 3);
            const bf16x8 bh = *reinterpret_cast<const bf16x8*>(&Bh[boff]);
            acc[t] = __builtin_amdgcn_mfma_f32_16x16x32_bf16(ah, bh, acc[t], 0, 0, 0);
        }
    }
    #pragma unroll
    for (int t = 0; t < 4; ++t) {
        #pragma unroll
        for (int r = 0; r < 4; ++r) {
            float v = acc[t][r];
            if (RELU) v = fmaxf(v, 0.0f);
            const size_t off = (size_t)(node0 + w * 16 + g * 4 + r) * 64 + t * 16 + rl;
            if (BF16OUT) outb[off] = f2bf(v);
            else         outf[off] = v;
        }
    }
}

extern "C" void kernel_launch(void* const* d_in, const int* in_sizes, int n_in,
                              void* d_out, int out_size, void* d_ws, size_t ws_size,
                              hipStream_t stream)
{
    const float* x    = (const float*)d_in[0];
    const int*   ei   = (const int*)d_in[1];
    const int    E    = in_sizes[1] / 2;     // 1,048,576
    const int*   src  = ei;
    const int*   dstp = ei + E;
    const float* wl1 = (const float*)d_in[2];
    const float* b1  = (const float*)d_in[3];
    const float* wr1 = (const float*)d_in[4];
    const float* wl2 = (const float*)d_in[5];
    const float* b2  = (const float*)d_in[6];
    const float* wr2 = (const float*)d_in[7];
    const float* wl3 = (const float*)d_in[8];
    const float* b3  = (const float*)d_in[9];
    const float* wr3 = (const float*)d_in[10];
    float* out = (float*)d_out;
    const int n = in_sizes[0] / D;           // 65536

    // workspace (~24.5 MiB):
    // prim 4M | ovfl 4M | cursor 256K | cnts 256K | Wh 48K |
    // unionArea 16M = { binned 12.6M (dead after binB) / aggb 8M + hb2 8M }
    unsigned short* prim = (unsigned short*)d_ws;
    unsigned short* ovfl = prim + (size_t)n * PCAP;
    int*   cursor = (int*)(ovfl + (size_t)n * PCAP);
    int*   cnts   = cursor + n;
    unsigned short* Wh  = (unsigned short*)(cnts + NBUCK * NBINA);
    unsigned short* aggb = Wh + 3 * D * 128;             // union start
    unsigned* binned = (unsigned*)aggb;                  // aliased (dies at binB end)
    unsigned short* hb2 = aggb + (size_t)n * D;

    // bf16 tables: xb = d_out half0 (dead after layer1), hb1 = d_out half1
    // (dead after layer2), hb2 in ws -> layer3 reads only ws, writes d_out fp32.
    unsigned short* xb  = (unsigned short*)d_out;
    unsigned short* hb1 = xb + (size_t)n * D;

    const int E4 = E / 4;
    const int nbConv = (n * 16) / 256;       // 4096

    mega_kernel<<<NBINA + nbConv + 12, 256, 0, stream>>>(
        src, dstp, E4, binned, cnts,
        (const float4*)x, (ushort4v*)xb, n * 16, nbConv,
        wl1, wr1, wl2, wr2, wl3, wr3, Wh);
    binB_kernel<<<NBUCK, 256, 0, stream>>>(binned, cnts, prim, ovfl, cursor);

    const int gatherBlocks = n / 8;      // 2 nodes per wave, 32768 waves
    const int gemmBlocks   = n / 64;     // 1024

    // layer 1: xb -> hb1 (ReLU, bf16)
    gather_b<<<gatherBlocks, 256, 0, stream>>>(xb, prim, ovfl, cursor, aggb, n);
    gemm_mfma<true, true><<<gemmBlocks, 256, 0, stream>>>(
        aggb, xb, Wh, b1, hb1, nullptr);

    // layer 2: hb1 -> hb2 (ReLU, bf16, into ws)
    gather_b<<<gatherBlocks, 256, 0, stream>>>(hb1, prim, ovfl, cursor, aggb, n);
    gemm_mfma<true, true><<<gemmBlocks, 256, 0, stream>>>(
        aggb, hb1, Wh + D * 128, b2, hb2, nullptr);

    // layer 3: hb2 -> d_out fp32 (reads only ws buffers)
    gather_b<<<gatherBlocks, 256, 0, stream>>>(hb2, prim, ovfl, cursor, aggb, n);
    gemm_mfma<false, false><<<gemmBlocks, 256, 0, stream>>>(
        aggb, hb2, Wh + 2 * D * 128, b3, nullptr, out);
}